// Round 3
// baseline (564.418 us; speedup 1.0000x reference)
//
#include <hip/hip_runtime.h>
#include <hip/hip_bf16.h>

#define BB 16
#define DDIM 256
#define TLEN 4096
#define KCODES 1024
#define NQ (BB*TLEN)   // 65536
#define QBLK 32        // queries per block in k_dist
#define CBLK 128       // codes per k-tile in k_dist

#define FLT_MAX_C 3.402823466e+38f

// ---------------------------------------------------------------------------
// numpy pairwise sum-of-squares over 256 elements (stride in elements).
// n=256 -> two 128-blocks; each 128-block: 8 accumulators, combined
// ((r0+r1)+(r2+r3))+((r4+r5)+(r6+r7)); final th0+th1. Squares rounded
// separately (numpy materializes z*z then sums).
// ---------------------------------------------------------------------------
__device__ __forceinline__ float np_sumsq_256(const float* p, int stride) {
  float th[2];
#pragma unroll
  for (int h = 0; h < 2; ++h) {
    const float* q = p + (size_t)h * 128 * (size_t)stride;
    float r[8];
#pragma unroll
    for (int j = 0; j < 8; ++j) {
      float v = q[(size_t)j * (size_t)stride];
      r[j] = __fmul_rn(v, v);
    }
    for (int i = 8; i < 128; i += 8) {
#pragma unroll
      for (int j = 0; j < 8; ++j) {
        float v = q[(size_t)(i + j) * (size_t)stride];
        r[j] = __fadd_rn(r[j], __fmul_rn(v, v));
      }
    }
    th[h] = __fadd_rn(__fadd_rn(__fadd_rn(r[0], r[1]), __fadd_rn(r[2], r[3])),
                      __fadd_rn(__fadd_rn(r[4], r[5]), __fadd_rn(r[6], r[7])));
  }
  return __fadd_rn(th[0], th[1]);
}

// ---------------------------------------------------------------------------
// k_prep: embT[d][k] = emb[k][d]; e2[k] = numpy-pairwise sum(emb[k]^2)
// ---------------------------------------------------------------------------
__global__ void k_prep(const float* __restrict__ emb, float* __restrict__ embT,
                       float* __restrict__ e2) {
  const int k = blockIdx.x;
  const int d = threadIdx.x;
  __shared__ float row[DDIM];
  float v = emb[(size_t)k * DDIM + d];
  row[d] = v;
  embT[(size_t)d * KCODES + k] = v;
  __syncthreads();
  if (d == 0) e2[k] = np_sumsq_256(row, 1);
}

// ---------------------------------------------------------------------------
// k_z2: z2[n] = numpy-pairwise sum over d of z[b,d,t]^2  (n = b*T + t)
// ---------------------------------------------------------------------------
__global__ void k_z2(const float* __restrict__ z, float* __restrict__ z2) {
  const int n = blockIdx.x * 256 + threadIdx.x;
  const int b = n >> 12;
  const int t = n & (TLEN - 1);
  const float* p = z + (size_t)b * DDIM * TLEN + t;  // stride TLEN over d
  z2[n] = np_sumsq_256(p, TLEN);
}

// ---------------------------------------------------------------------------
// k_dist: 32 queries/block, 8 k-tiles of 128 codes. Per thread 4 queries x
// 4 codes. dot = sequential fp32 FMA chain over d ascending (single
// accumulator = OpenBLAS sgemm microkernel order, K=256 fits one KC panel).
// dist = fp32(fp32(z2+e2) - fp32(2*dot)). argmin strict-<, k ascending
// within thread; cross-lane reduce with lowest-index tie-break => global
// first-occurrence argmin (numpy semantics).
// LDS: zs 32KB + es 32KB = 64KB.
// ---------------------------------------------------------------------------
__global__ __launch_bounds__(256, 2)
void k_dist(const float* __restrict__ z, const float* __restrict__ embT,
            const float* __restrict__ z2, const float* __restrict__ e2,
            int* __restrict__ idx, int* __restrict__ hist,
            double* __restrict__ lossp) {
  __shared__ float zs[DDIM * QBLK];   // [d][q]  256x32
  __shared__ float es[64 * CBLK];     // [dd][c] 64x128
  const int tid = threadIdx.x;
  const int tx = tid & 31;   // code group (x4) -> 128 codes
  const int ty = tid >> 5;   // query group (x4) -> 32 queries
  const int n0 = blockIdx.x * QBLK;
  const int b = n0 >> 12;
  const int t0 = n0 & (TLEN - 1);
  const float* zp = z + (size_t)b * DDIM * TLEN + t0;

  // stage zs: 2048 float4 slots; slot s -> row d=s>>3, col group g=s&7
#pragma unroll
  for (int i = 0; i < 8; ++i) {
    int s = i * 256 + tid;
    int d = s >> 3, g = s & 7;
    float4 v = *(const float4*)(zp + (size_t)d * TLEN + g * 4);
    *((float4*)&zs[d * QBLK + g * 4]) = v;
  }

  float z2q[4];
#pragma unroll
  for (int i = 0; i < 4; ++i) z2q[i] = z2[n0 + ty * 4 + i];

  float best[4] = {FLT_MAX_C, FLT_MAX_C, FLT_MAX_C, FLT_MAX_C};
  int bidx[4] = {0, 0, 0, 0};
  __syncthreads();

  for (int kt = 0; kt < KCODES / CBLK; ++kt) {  // 8 tiles
    float acc[4][4];
#pragma unroll
    for (int i = 0; i < 4; ++i)
#pragma unroll
      for (int j = 0; j < 4; ++j) acc[i][j] = 0.f;

    for (int dc = 0; dc < 4; ++dc) {
      // stage es: slot s -> row r=s>>5, col group c4=s&31
#pragma unroll
      for (int i = 0; i < 8; ++i) {
        int s = i * 256 + tid;
        int r = s >> 5, c4 = s & 31;
        float4 v = *(const float4*)(embT + (size_t)(dc * 64 + r) * KCODES +
                                    kt * CBLK + c4 * 4);
        *((float4*)&es[r * CBLK + c4 * 4]) = v;
      }
      __syncthreads();
#pragma unroll 8
      for (int dd = 0; dd < 64; ++dd) {
        float4 zv = *((const float4*)&zs[(dc * 64 + dd) * QBLK + ty * 4]);
        float4 ev = *((const float4*)&es[dd * CBLK + tx * 4]);
        float zr[4] = {zv.x, zv.y, zv.z, zv.w};
        float er[4] = {ev.x, ev.y, ev.z, ev.w};
#pragma unroll
        for (int i = 0; i < 4; ++i)
#pragma unroll
          for (int j = 0; j < 4; ++j)
            acc[i][j] = __fmaf_rn(zr[i], er[j], acc[i][j]);
      }
      __syncthreads();
    }
    // epilogue: distances + running argmin (k ascending within thread)
    float e2c[4];
#pragma unroll
    for (int j = 0; j < 4; ++j) e2c[j] = e2[kt * CBLK + tx * 4 + j];
#pragma unroll
    for (int i = 0; i < 4; ++i) {
#pragma unroll
      for (int j = 0; j < 4; ++j) {
        float dist = __fsub_rn(__fadd_rn(z2q[i], e2c[j]),
                               __fmul_rn(2.0f, acc[i][j]));
        int kg = kt * CBLK + tx * 4 + j;
        if (dist < best[i]) { best[i] = dist; bidx[i] = kg; }
      }
    }
  }

  // reduce (best, idx) across the 32 tx lanes (same ty, within one wave)
#pragma unroll
  for (int i = 0; i < 4; ++i) {
#pragma unroll
    for (int m = 1; m < 32; m <<= 1) {
      float od = __shfl_xor(best[i], m, 64);
      int oi = __shfl_xor(bidx[i], m, 64);
      if (od < best[i] || (od == best[i] && oi < bidx[i])) {
        best[i] = od; bidx[i] = oi;
      }
    }
  }

  double lsum = 0.0;
  if (tx == 0) {
#pragma unroll
    for (int i = 0; i < 4; ++i) {
      int n = n0 + ty * 4 + i;
      idx[n] = bidx[i];
      atomicAdd(&hist[bidx[i]], 1);
      lsum += (double)best[i];
    }
  }
  // per-wave deterministic partial for the loss
#pragma unroll
  for (int m = 1; m < 64; m <<= 1) lsum += __shfl_xor(lsum, m, 64);
  if ((tid & 63) == 0) lossp[blockIdx.x * 4 + (tid >> 6)] = lsum;
}

// ---------------------------------------------------------------------------
// k_idxout: indices as FLOAT32 (exact for values <= 1024)
// ---------------------------------------------------------------------------
__global__ void k_idxout(const int* __restrict__ idx,
                         float* __restrict__ oidx) {
  int n = blockIdx.x * 256 + threadIdx.x;
  oidx[n] = (float)(idx[n] & (KCODES - 1));
}

// ---------------------------------------------------------------------------
// k_gather: out[b,d,t] = emb[idx[b,t], d] as FLOAT32; one block per (b,d).
// ---------------------------------------------------------------------------
__global__ void k_gather(const float* __restrict__ embT,
                         const int* __restrict__ idx,
                         float* __restrict__ out) {
  __shared__ float er[KCODES];
  const int blk = blockIdx.x;  // b*D + d
  const int bq = blk >> 8;
  const int d = blk & 255;
  const int tid = threadIdx.x;
  *((float4*)&er[tid * 4]) =
      *((const float4*)(embT + (size_t)d * KCODES + tid * 4));
  __syncthreads();
  const int* ip = idx + (size_t)bq * TLEN;
  float* op = out + (size_t)blk * TLEN;
#pragma unroll
  for (int c = 0; c < 16; ++c) {
    int t = c * 256 + tid;
    int kk = ip[t] & (KCODES - 1);
    op[t] = er[kk];
  }
}

// ---------------------------------------------------------------------------
// k_final: loss = 0.25 * sum(min dists)/(N*D); perplexity from histogram.
// FLOAT32 outputs. Deterministic fixed-tree reductions, single block.
// ---------------------------------------------------------------------------
__global__ void k_final(const int* __restrict__ hist,
                        const double* __restrict__ lossp,
                        float* __restrict__ out2) {
  const int tid = threadIdx.x;  // 256
  double ls = 0.0;
  for (int i = 0; i < 32; ++i) ls += lossp[tid * 32 + i];  // 8192 partials
  float es = 0.f;
  for (int i = tid; i < KCODES; i += 256) {
    float p = (float)hist[i] / 65536.0f;
    es += p * logf(p + 1e-10f);
  }
#pragma unroll
  for (int m = 1; m < 64; m <<= 1) {
    ls += __shfl_xor(ls, m, 64);
    es += __shfl_xor(es, m, 64);
  }
  __shared__ double lw[4];
  __shared__ float ew[4];
  if ((tid & 63) == 0) { lw[tid >> 6] = ls; ew[tid >> 6] = es; }
  __syncthreads();
  if (tid == 0) {
    double lt = lw[0] + lw[1] + lw[2] + lw[3];
    float et = ew[0] + ew[1] + ew[2] + ew[3];
    float loss = 0.25f * (float)(lt / (double)((long long)NQ * DDIM));
    float perp = expf(-et);
    out2[0] = loss;
    out2[1] = perp;
  }
}

// ---------------------------------------------------------------------------
// workspace layout (bytes):
//   embT  : 0         .. 1048576   (D*K floats)
//   e2    : 1048576   .. 1052672   (K floats)
//   z2    : 1052672   .. 1314816   (N floats)
//   idx   : 1314816   .. 1576960   (N ints)
//   hist  : 1576960   .. 1581056   (K ints)         <- memset each launch
//   lossp : 1581056   .. 1646592   (8192 doubles)   <- fully written
// total ~1.57 MB
// ---------------------------------------------------------------------------
extern "C" void kernel_launch(void* const* d_in, const int* in_sizes, int n_in,
                              void* d_out, int out_size, void* d_ws, size_t ws_size,
                              hipStream_t stream) {
  const float* z = (const float*)d_in[0];
  const float* emb = (const float*)d_in[1];
  float* out = (float*)d_out;   // FLOAT32 output buffer (reference dtype)

  char* ws = (char*)d_ws;
  float* embT = (float*)(ws);
  float* e2 = (float*)(ws + 1048576);
  float* z2 = (float*)(ws + 1052672);
  int* idx = (int*)(ws + 1314816);
  int* hist = (int*)(ws + 1576960);
  double* lossp = (double*)(ws + 1581056);

  // f32 element offsets: [out (B*D*T)] [indices (N)] [loss, perp]
  float* oidx = out + ((size_t)out_size - 2 - NQ);
  float* out2 = out + ((size_t)out_size - 2);

  hipMemsetAsync(hist, 0, KCODES * sizeof(int), stream);

  k_prep<<<KCODES, 256, 0, stream>>>(emb, embT, e2);
  k_z2<<<NQ / 256, 256, 0, stream>>>(z, z2);
  k_dist<<<NQ / QBLK, 256, 0, stream>>>(z, embT, z2, e2, idx, hist, lossp);
  k_idxout<<<NQ / 256, 256, 0, stream>>>(idx, oidx);
  k_gather<<<BB * DDIM, 256, 0, stream>>>(embT, idx, out);
  k_final<<<1, 256, 0, stream>>>(hist, lossp, out2);
}

// Round 4
// 512.845 us; speedup vs baseline: 1.1006x; 1.1006x over previous
//
#include <hip/hip_runtime.h>
#include <hip/hip_bf16.h>

#define BB 16
#define DDIM 256
#define TLEN 4096
#define KCODES 1024
#define NQ (BB*TLEN)   // 65536
#define QBLK 32        // queries per block in k_dist (8 per wave)

#define FLT_MAX_C 3.402823466e+38f

// ---------------------------------------------------------------------------
// numpy pairwise sum-of-squares over 256 elements (stride in elements).
// ---------------------------------------------------------------------------
__device__ __forceinline__ float np_sumsq_256(const float* p, int stride) {
  float th[2];
#pragma unroll
  for (int h = 0; h < 2; ++h) {
    const float* q = p + (size_t)h * 128 * (size_t)stride;
    float r[8];
#pragma unroll
    for (int j = 0; j < 8; ++j) {
      float v = q[(size_t)j * (size_t)stride];
      r[j] = __fmul_rn(v, v);
    }
    for (int i = 8; i < 128; i += 8) {
#pragma unroll
      for (int j = 0; j < 8; ++j) {
        float v = q[(size_t)(i + j) * (size_t)stride];
        r[j] = __fadd_rn(r[j], __fmul_rn(v, v));
      }
    }
    th[h] = __fadd_rn(__fadd_rn(__fadd_rn(r[0], r[1]), __fadd_rn(r[2], r[3])),
                      __fadd_rn(__fadd_rn(r[4], r[5]), __fadd_rn(r[6], r[7])));
  }
  return __fadd_rn(th[0], th[1]);
}

// ---------------------------------------------------------------------------
// k_prep: embT[d][k] = emb[k][d]; e2[k] = numpy-pairwise sum(emb[k]^2)
// ---------------------------------------------------------------------------
__global__ void k_prep(const float* __restrict__ emb, float* __restrict__ embT,
                       float* __restrict__ e2) {
  const int k = blockIdx.x;
  const int d = threadIdx.x;
  __shared__ float row[DDIM];
  float v = emb[(size_t)k * DDIM + d];
  row[d] = v;
  embT[(size_t)d * KCODES + k] = v;
  __syncthreads();
  if (d == 0) e2[k] = np_sumsq_256(row, 1);
}

// ---------------------------------------------------------------------------
// k_z2: z2[n] = numpy-pairwise sum over d of z[b,d,t]^2  (n = b*T + t)
// ---------------------------------------------------------------------------
__global__ void k_z2(const float* __restrict__ z, float* __restrict__ z2) {
  const int n = blockIdx.x * 256 + threadIdx.x;
  const int b = n >> 12;
  const int t = n & (TLEN - 1);
  const float* p = z + (size_t)b * DDIM * TLEN + t;  // stride TLEN over d
  z2[n] = np_sumsq_256(p, TLEN);
}

// ---------------------------------------------------------------------------
// k_dist v2: 32 queries/block = 4 waves x 8 queries. Each wave's 64 lanes
// share the SAME 8 queries (z read as LDS broadcast — conflict-free) and
// each lane owns 16 codes (4 chunks of 4: k = jc*256 + lane*4 + jj), read
// as float4 DIRECTLY from L2-resident embT (no staging, no k-loop barriers).
// Per d-step: 2 LDS broadcast reads + 4 global b128 + 128 FMA -> VALU-bound.
// Exactness: dot per (q,k) = single sequential fp32 FMA chain, d ascending
// (numpy/BLAS order, proven bit-exact in round 3). dist/argmin chain
// identical to round 3.
// ---------------------------------------------------------------------------
__global__ __launch_bounds__(256, 2)
void k_dist(const float* __restrict__ z, const float* __restrict__ embT,
            const float* __restrict__ z2, const float* __restrict__ e2,
            int* __restrict__ idx, int* __restrict__ hist,
            double* __restrict__ lossp) {
  __shared__ float zs[DDIM * QBLK];  // [d][q] 256x32, 32KB
  const int tid = threadIdx.x;
  const int lane = tid & 63;
  const int wave = tid >> 6;
  const int n0 = blockIdx.x * QBLK;
  const int b = n0 >> 12;
  const int t0 = n0 & (TLEN - 1);
  const float* zp = z + (size_t)b * DDIM * TLEN + t0;

  // stage zs[d*32+q]: linear index = d*32+q; coalesced global reads
#pragma unroll
  for (int i = 0; i < 32; ++i) {
    int s = i * 256 + tid;
    zs[s] = zp[(size_t)(s >> 5) * TLEN + (s & 31)];
  }
  __syncthreads();

  const int wq = wave * 8;            // this wave's first query (block-local)
  const float* eb = embT + lane * 4;  // lane's base column

  float acc[8][16];
#pragma unroll
  for (int i = 0; i < 8; ++i)
#pragma unroll
    for (int j = 0; j < 16; ++j) acc[i][j] = 0.f;

  // main loop: d ascending, single fp32 FMA chain per (q,k)
#pragma unroll 4
  for (int d = 0; d < DDIM; ++d) {
    float4 za = *(const float4*)&zs[d * QBLK + wq];      // broadcast
    float4 zb = *(const float4*)&zs[d * QBLK + wq + 4];  // broadcast
    const float* er = eb + (size_t)d * KCODES;
    float4 e0 = *(const float4*)(er);
    float4 e1 = *(const float4*)(er + 256);
    float4 ev2 = *(const float4*)(er + 512);
    float4 e3 = *(const float4*)(er + 768);
    float zr[8] = {za.x, za.y, za.z, za.w, zb.x, zb.y, zb.z, zb.w};
    float ee[16] = {e0.x, e0.y, e0.z, e0.w, e1.x, e1.y, e1.z, e1.w,
                    ev2.x, ev2.y, ev2.z, ev2.w, e3.x, e3.y, e3.z, e3.w};
#pragma unroll
    for (int i = 0; i < 8; ++i)
#pragma unroll
      for (int j = 0; j < 16; ++j)
        acc[i][j] = __fmaf_rn(zr[i], ee[j], acc[i][j]);
  }

  // epilogue: exact dist chain + first-occurrence argmin
  float e2c[16];
#pragma unroll
  for (int jc = 0; jc < 4; ++jc) {
    float4 v = *(const float4*)(e2 + jc * 256 + lane * 4);
    e2c[jc * 4 + 0] = v.x; e2c[jc * 4 + 1] = v.y;
    e2c[jc * 4 + 2] = v.z; e2c[jc * 4 + 3] = v.w;
  }

  double lsum = 0.0;
#pragma unroll
  for (int i = 0; i < 8; ++i) {
    const int n = n0 + wq + i;
    const float z2q = z2[n];  // wave-uniform
    float best = FLT_MAX_C;
    int bi = 0;
#pragma unroll
    for (int jc = 0; jc < 4; ++jc) {
#pragma unroll
      for (int jj = 0; jj < 4; ++jj) {
        float dist = __fsub_rn(__fadd_rn(z2q, e2c[jc * 4 + jj]),
                               __fmul_rn(2.0f, acc[i][jc * 4 + jj]));
        int kg = jc * 256 + lane * 4 + jj;  // ascending k within thread
        if (dist < best) { best = dist; bi = kg; }
      }
    }
    // 64-lane butterfly min with lowest-index tie-break
#pragma unroll
    for (int m = 1; m < 64; m <<= 1) {
      float od = __shfl_xor(best, m, 64);
      int oi = __shfl_xor(bi, m, 64);
      if (od < best || (od == best && oi < bi)) { best = od; bi = oi; }
    }
    if (lane == 0) {
      idx[n] = bi;
      atomicAdd(&hist[bi], 1);
      lsum += (double)best;
    }
  }
  if (lane == 0) lossp[blockIdx.x * 4 + wave] = lsum;
}

// ---------------------------------------------------------------------------
// k_idxout: indices as FLOAT32
// ---------------------------------------------------------------------------
__global__ void k_idxout(const int* __restrict__ idx,
                         float* __restrict__ oidx) {
  int n = blockIdx.x * 256 + threadIdx.x;
  oidx[n] = (float)(idx[n] & (KCODES - 1));
}

// ---------------------------------------------------------------------------
// k_gather: out[b,d,t] = emb[idx[b,t], d]; one block per (b,d)
// ---------------------------------------------------------------------------
__global__ void k_gather(const float* __restrict__ embT,
                         const int* __restrict__ idx,
                         float* __restrict__ out) {
  __shared__ float er[KCODES];
  const int blk = blockIdx.x;  // b*D + d
  const int bq = blk >> 8;
  const int d = blk & 255;
  const int tid = threadIdx.x;
  *((float4*)&er[tid * 4]) =
      *((const float4*)(embT + (size_t)d * KCODES + tid * 4));
  __syncthreads();
  const int* ip = idx + (size_t)bq * TLEN;
  float* op = out + (size_t)blk * TLEN;
#pragma unroll
  for (int c = 0; c < 16; ++c) {
    int t = c * 256 + tid;
    int kk = ip[t] & (KCODES - 1);
    op[t] = er[kk];
  }
}

// ---------------------------------------------------------------------------
// k_final: loss and perplexity (deterministic fixed-tree reductions)
// ---------------------------------------------------------------------------
__global__ void k_final(const int* __restrict__ hist,
                        const double* __restrict__ lossp,
                        float* __restrict__ out2) {
  const int tid = threadIdx.x;  // 256
  double ls = 0.0;
  for (int i = 0; i < 32; ++i) ls += lossp[tid * 32 + i];  // 8192 partials
  float es = 0.f;
  for (int i = tid; i < KCODES; i += 256) {
    float p = (float)hist[i] / 65536.0f;
    es += p * logf(p + 1e-10f);
  }
#pragma unroll
  for (int m = 1; m < 64; m <<= 1) {
    ls += __shfl_xor(ls, m, 64);
    es += __shfl_xor(es, m, 64);
  }
  __shared__ double lw[4];
  __shared__ float ew[4];
  if ((tid & 63) == 0) { lw[tid >> 6] = ls; ew[tid >> 6] = es; }
  __syncthreads();
  if (tid == 0) {
    double lt = lw[0] + lw[1] + lw[2] + lw[3];
    float et = ew[0] + ew[1] + ew[2] + ew[3];
    float loss = 0.25f * (float)(lt / (double)((long long)NQ * DDIM));
    float perp = expf(-et);
    out2[0] = loss;
    out2[1] = perp;
  }
}

// ---------------------------------------------------------------------------
// workspace layout (bytes):
//   embT  : 0         .. 1048576   (D*K floats)
//   e2    : 1048576   .. 1052672   (K floats)
//   z2    : 1052672   .. 1314816   (N floats)
//   idx   : 1314816   .. 1576960   (N ints)
//   hist  : 1576960   .. 1581056   (K ints)         <- memset each launch
//   lossp : 1581056   .. 1646592   (8192 doubles)   <- fully written
// ---------------------------------------------------------------------------
extern "C" void kernel_launch(void* const* d_in, const int* in_sizes, int n_in,
                              void* d_out, int out_size, void* d_ws, size_t ws_size,
                              hipStream_t stream) {
  const float* z = (const float*)d_in[0];
  const float* emb = (const float*)d_in[1];
  float* out = (float*)d_out;

  char* ws = (char*)d_ws;
  float* embT = (float*)(ws);
  float* e2 = (float*)(ws + 1048576);
  float* z2 = (float*)(ws + 1052672);
  int* idx = (int*)(ws + 1314816);
  int* hist = (int*)(ws + 1576960);
  double* lossp = (double*)(ws + 1581056);

  float* oidx = out + ((size_t)out_size - 2 - NQ);
  float* out2 = out + ((size_t)out_size - 2);

  hipMemsetAsync(hist, 0, KCODES * sizeof(int), stream);

  k_prep<<<KCODES, 256, 0, stream>>>(emb, embT, e2);
  k_z2<<<NQ / 256, 256, 0, stream>>>(z, z2);
  k_dist<<<NQ / QBLK, 256, 0, stream>>>(z, embT, z2, e2, idx, hist, lossp);
  k_idxout<<<NQ / 256, 256, 0, stream>>>(idx, oidx);
  k_gather<<<BB * DDIM, 256, 0, stream>>>(embT, idx, out);
  k_final<<<1, 256, 0, stream>>>(hist, lossp, out2);
}

// Round 5
// 341.593 us; speedup vs baseline: 1.6523x; 1.5013x over previous
//
#include <hip/hip_runtime.h>
#include <hip/hip_bf16.h>

#define BB 16
#define DDIM 256
#define TLEN 4096
#define KCODES 1024
#define NQ (BB*TLEN)   // 65536
#define MAXC 32
#define DELTA 4e-4f

#define FLT_MAX_C 3.402823466e+38f

using short8 = __attribute__((ext_vector_type(8))) short;
using f32x4  = __attribute__((ext_vector_type(4))) float;

// RNE fp32 -> bf16 (bit pattern), and back
__device__ __forceinline__ unsigned short f2bf(float x) {
  unsigned u = __float_as_uint(x);
  unsigned r = (u + 0x7fffu + ((u >> 16) & 1u)) >> 16;
  return (unsigned short)r;
}
__device__ __forceinline__ float bf2f(unsigned short h) {
  return __uint_as_float(((unsigned)h) << 16);
}

// ---------------------------------------------------------------------------
// numpy pairwise sum-of-squares over 256 elements (stride in elements).
// ---------------------------------------------------------------------------
__device__ __forceinline__ float np_sumsq_256(const float* p, int stride) {
  float th[2];
#pragma unroll
  for (int h = 0; h < 2; ++h) {
    const float* q = p + (size_t)h * 128 * (size_t)stride;
    float r[8];
#pragma unroll
    for (int j = 0; j < 8; ++j) {
      float v = q[(size_t)j * (size_t)stride];
      r[j] = __fmul_rn(v, v);
    }
    for (int i = 8; i < 128; i += 8) {
#pragma unroll
      for (int j = 0; j < 8; ++j) {
        float v = q[(size_t)(i + j) * (size_t)stride];
        r[j] = __fadd_rn(r[j], __fmul_rn(v, v));
      }
    }
    th[h] = __fadd_rn(__fadd_rn(__fadd_rn(r[0], r[1]), __fadd_rn(r[2], r[3])),
                      __fadd_rn(__fadd_rn(r[4], r[5]), __fadd_rn(r[6], r[7])));
  }
  return __fadd_rn(th[0], th[1]);
}

// ---------------------------------------------------------------------------
// k_prep: embT (for gather), e2 exact, bf16 hi/lo split of emb
// ---------------------------------------------------------------------------
__global__ void k_prep(const float* __restrict__ emb, float* __restrict__ embT,
                       float* __restrict__ e2, short* __restrict__ ebh,
                       short* __restrict__ ebl) {
  const int k = blockIdx.x;
  const int d = threadIdx.x;
  __shared__ float row[DDIM];
  float v = emb[(size_t)k * DDIM + d];
  row[d] = v;
  embT[(size_t)d * KCODES + k] = v;
  unsigned short h = f2bf(v);
  ebh[(size_t)k * DDIM + d] = (short)h;
  ebl[(size_t)k * DDIM + d] = (short)f2bf(v - bf2f(h));
  __syncthreads();
  if (d == 0) e2[k] = np_sumsq_256(row, 1);
}

// ---------------------------------------------------------------------------
// k_z2: exact numpy-pairwise sum over d of z[b,d,t]^2
// ---------------------------------------------------------------------------
__global__ void k_z2(const float* __restrict__ z, float* __restrict__ z2) {
  const int n = blockIdx.x * 256 + threadIdx.x;
  const int b = n >> 12;
  const int t = n & (TLEN - 1);
  const float* p = z + (size_t)b * DDIM * TLEN + t;
  z2[n] = np_sumsq_256(p, TLEN);
}

// ---------------------------------------------------------------------------
// k_mdist: MFMA approx distances (bf16 hi/lo x3) + exact fp32 recheck of
// candidates within DELTA of the per-query approx min.
// Block: 512 threads = 8 waves; 64 queries; wave w owns codes [w*128,(w+1)*128).
// Per wave: mt=0..3 (16 q each), nt=0..7 (16 codes), ks=0..7 (32 d).
// A frag (lane l): q = mt*16 + (l&15), d = ks*32 + (l>>4)*8 + j
// B frag (lane l): k = base + nt*16 + (l&15), same d slice
// C/D: col(code)=lane&15, row(q)=(lane>>4)*4 + reg
// ---------------------------------------------------------------------------
__global__ __launch_bounds__(512, 2)
void k_mdist(const float* __restrict__ z, const float* __restrict__ emb,
             const short* __restrict__ ebh, const short* __restrict__ ebl,
             const float* __restrict__ e2, const float* __restrict__ z2,
             int* __restrict__ idx, int* __restrict__ hist,
             double* __restrict__ lossp) {
  const int tid = threadIdx.x;
  const int lane = tid & 63;
  const int w = tid >> 6;
  const int g = lane >> 4;
  const int c = lane & 15;
  const int n0 = blockIdx.x * 64;
  const int b = n0 >> 12;
  const int t0 = n0 & (TLEN - 1);
  const int kbase = w * 128;
  const float* zbase = z + (size_t)b * DDIM * TLEN + t0;

  f32x4 acc[4][8];
#pragma unroll
  for (int mt = 0; mt < 4; ++mt)
#pragma unroll
    for (int nt = 0; nt < 8; ++nt) {
      f32x4 zz = {0.f, 0.f, 0.f, 0.f};
      acc[mt][nt] = zz;
    }

  for (int ks = 0; ks < 8; ++ks) {
    short8 ah[4], al[4];
#pragma unroll
    for (int mt = 0; mt < 4; ++mt) {
      const int q = mt * 16 + c;
      const int dbase = ks * 32 + g * 8;
      float av[8];
#pragma unroll
      for (int j = 0; j < 8; ++j)
        av[j] = zbase[(size_t)(dbase + j) * TLEN + q];
#pragma unroll
      for (int j = 0; j < 8; ++j) {
        unsigned short h = f2bf(av[j]);
        ah[mt][j] = (short)h;
        al[mt][j] = (short)f2bf(av[j] - bf2f(h));
      }
    }
#pragma unroll
    for (int nt = 0; nt < 8; ++nt) {
      const size_t eo = (size_t)(kbase + nt * 16 + c) * DDIM + ks * 32 + g * 8;
      short8 bh = *(const short8*)(ebh + eo);
      short8 bl = *(const short8*)(ebl + eo);
#pragma unroll
      for (int mt = 0; mt < 4; ++mt) {
        acc[mt][nt] = __builtin_amdgcn_mfma_f32_16x16x32_bf16(ah[mt], bh, acc[mt][nt], 0, 0, 0);
        acc[mt][nt] = __builtin_amdgcn_mfma_f32_16x16x32_bf16(al[mt], bh, acc[mt][nt], 0, 0, 0);
        acc[mt][nt] = __builtin_amdgcn_mfma_f32_16x16x32_bf16(ah[mt], bl, acc[mt][nt], 0, 0, 0);
      }
    }
  }

  // ---- epilogue: approx score s = e2[k] - 2*dot ----
  __shared__ float sm[8][64];
  __shared__ float qmin[64];
  __shared__ int cnt[64];
  __shared__ int ovf[64];
  __shared__ int cand[64][MAXC];
  __shared__ float bd[64][8];
  __shared__ int bk[64][8];

  float e2c[8];
#pragma unroll
  for (int nt = 0; nt < 8; ++nt) e2c[nt] = e2[kbase + nt * 16 + c];

  float smin[4][4];
#pragma unroll
  for (int mt = 0; mt < 4; ++mt)
#pragma unroll
    for (int r = 0; r < 4; ++r) {
      float m = FLT_MAX_C;
#pragma unroll
      for (int nt = 0; nt < 8; ++nt)
        m = fminf(m, e2c[nt] - 2.0f * acc[mt][nt][r]);
      smin[mt][r] = m;
    }
  // min across the 16 lanes (c) sharing the same q
#pragma unroll
  for (int mt = 0; mt < 4; ++mt)
#pragma unroll
    for (int r = 0; r < 4; ++r) {
#pragma unroll
      for (int m = 1; m < 16; m <<= 1)
        smin[mt][r] = fminf(smin[mt][r], __shfl_xor(smin[mt][r], m, 64));
    }
  if (c == 0) {
#pragma unroll
    for (int mt = 0; mt < 4; ++mt)
#pragma unroll
      for (int r = 0; r < 4; ++r)
        sm[w][mt * 16 + g * 4 + r] = smin[mt][r];
  }
  if (tid < 64) { cnt[tid] = 0; ovf[tid] = 0; }
  __syncthreads();
  if (tid < 64) {
    float m = sm[0][tid];
#pragma unroll
    for (int wv = 1; wv < 8; ++wv) m = fminf(m, sm[wv][tid]);
    qmin[tid] = m;
  }
  __syncthreads();

  // candidate collection
#pragma unroll
  for (int mt = 0; mt < 4; ++mt)
#pragma unroll
    for (int r = 0; r < 4; ++r) {
      const int q = mt * 16 + g * 4 + r;
      const float lim = qmin[q] + DELTA;
#pragma unroll
      for (int nt = 0; nt < 8; ++nt) {
        float s = e2c[nt] - 2.0f * acc[mt][nt][r];
        if (s <= lim) {
          int p = atomicAdd(&cnt[q], 1);
          if (p < MAXC) cand[q][p] = kbase + nt * 16 + c;
          else ovf[q] = 1;
        }
      }
    }
  __syncthreads();

  // ---- exact recheck (reference fp32 chain), 8 slots per query ----
  {
    const int q = tid & 63;
    const int slot = tid >> 6;
    const int n = n0 + q;
    const float z2q = z2[n];
    const float* zq = zbase + q;  // z[b, d, t0+q], stride TLEN over d
    float bestd = FLT_MAX_C;
    int besti = (1 << 30);
    const bool all = (ovf[q] != 0) || (cnt[q] > MAXC);
    const int count = all ? KCODES : cnt[q];
    for (int ci = slot; ci < count; ci += 8) {
      const int k = all ? ci : cand[q][ci];
      const float* ek = emb + (size_t)k * DDIM;
      float a0 = 0.f;
      for (int d = 0; d < DDIM; ++d)
        a0 = __fmaf_rn(zq[(size_t)d * TLEN], ek[d], a0);
      float dist = __fsub_rn(__fadd_rn(z2q, e2[k]), __fmul_rn(2.0f, a0));
      if (dist < bestd || (dist == bestd && k < besti)) { bestd = dist; besti = k; }
    }
    bd[q][slot] = bestd;
    bk[q][slot] = besti;
  }
  __syncthreads();

  if (tid < 64) {
    float B = bd[tid][0];
    int K = bk[tid][0];
#pragma unroll
    for (int s = 1; s < 8; ++s) {
      float d2 = bd[tid][s];
      int k2 = bk[tid][s];
      if (d2 < B || (d2 == B && k2 < K)) { B = d2; K = k2; }
    }
    const int n = n0 + tid;
    idx[n] = K;
    atomicAdd(&hist[K], 1);
    double ls = (double)B;
#pragma unroll
    for (int m = 1; m < 64; m <<= 1) ls += __shfl_xor(ls, m, 64);
    if (tid == 0) lossp[blockIdx.x] = ls;
  }
}

// ---------------------------------------------------------------------------
// k_idxout: indices as FLOAT32
// ---------------------------------------------------------------------------
__global__ void k_idxout(const int* __restrict__ idx,
                         float* __restrict__ oidx) {
  int n = blockIdx.x * 256 + threadIdx.x;
  oidx[n] = (float)(idx[n] & (KCODES - 1));
}

// ---------------------------------------------------------------------------
// k_gather: out[b,d,t] = emb[idx[b,t], d]; one block per (b,d)
// ---------------------------------------------------------------------------
__global__ void k_gather(const float* __restrict__ embT,
                         const int* __restrict__ idx,
                         float* __restrict__ out) {
  __shared__ float er[KCODES];
  const int blk = blockIdx.x;  // b*D + d
  const int bq = blk >> 8;
  const int d = blk & 255;
  const int tid = threadIdx.x;
  *((float4*)&er[tid * 4]) =
      *((const float4*)(embT + (size_t)d * KCODES + tid * 4));
  __syncthreads();
  const int* ip = idx + (size_t)bq * TLEN;
  float* op = out + (size_t)blk * TLEN;
#pragma unroll
  for (int c = 0; c < 16; ++c) {
    int t = c * 256 + tid;
    int kk = ip[t] & (KCODES - 1);
    op[t] = er[kk];
  }
}

// ---------------------------------------------------------------------------
// k_final: loss and perplexity (deterministic fixed-tree reductions)
// lossp now has 1024 per-block partials.
// ---------------------------------------------------------------------------
__global__ void k_final(const int* __restrict__ hist,
                        const double* __restrict__ lossp,
                        float* __restrict__ out2) {
  const int tid = threadIdx.x;  // 256
  double ls = 0.0;
  for (int i = 0; i < 4; ++i) ls += lossp[tid * 4 + i];
  float es = 0.f;
  for (int i = tid; i < KCODES; i += 256) {
    float p = (float)hist[i] / 65536.0f;
    es += p * logf(p + 1e-10f);
  }
#pragma unroll
  for (int m = 1; m < 64; m <<= 1) {
    ls += __shfl_xor(ls, m, 64);
    es += __shfl_xor(es, m, 64);
  }
  __shared__ double lw[4];
  __shared__ float ew[4];
  if ((tid & 63) == 0) { lw[tid >> 6] = ls; ew[tid >> 6] = es; }
  __syncthreads();
  if (tid == 0) {
    double lt = lw[0] + lw[1] + lw[2] + lw[3];
    float et = ew[0] + ew[1] + ew[2] + ew[3];
    float loss = 0.25f * (float)(lt / (double)((long long)NQ * DDIM));
    float perp = expf(-et);
    out2[0] = loss;
    out2[1] = perp;
  }
}

// ---------------------------------------------------------------------------
// workspace layout (bytes):
//   embT  : 0        .. 1048576   (D*K floats)
//   e2    : 1048576  .. 1052672   (K floats)
//   z2    : 1052672  .. 1314816   (N floats)
//   idx   : 1314816  .. 1576960   (N ints)
//   hist  : 1576960  .. 1581056   (K ints)        <- memset each launch
//   lossp : 1581056  .. 1589248   (1024 doubles)  <- fully written
//   ebh   : 1589248  .. 2113536   (K*D bf16 hi)
//   ebl   : 2113536  .. 2637824   (K*D bf16 lo)
// total ~2.6 MB
// ---------------------------------------------------------------------------
extern "C" void kernel_launch(void* const* d_in, const int* in_sizes, int n_in,
                              void* d_out, int out_size, void* d_ws, size_t ws_size,
                              hipStream_t stream) {
  const float* z = (const float*)d_in[0];
  const float* emb = (const float*)d_in[1];
  float* out = (float*)d_out;

  char* ws = (char*)d_ws;
  float* embT = (float*)(ws);
  float* e2 = (float*)(ws + 1048576);
  float* z2 = (float*)(ws + 1052672);
  int* idx = (int*)(ws + 1314816);
  int* hist = (int*)(ws + 1576960);
  double* lossp = (double*)(ws + 1581056);
  short* ebh = (short*)(ws + 1589248);
  short* ebl = (short*)(ws + 2113536);

  float* oidx = out + ((size_t)out_size - 2 - NQ);
  float* out2 = out + ((size_t)out_size - 2);

  hipMemsetAsync(hist, 0, KCODES * sizeof(int), stream);

  k_prep<<<KCODES, 256, 0, stream>>>(emb, embT, e2, ebh, ebl);
  k_z2<<<NQ / 256, 256, 0, stream>>>(z, z2);
  k_mdist<<<NQ / 64, 512, 0, stream>>>(z, emb, ebh, ebl, e2, z2, idx, hist, lossp);
  k_idxout<<<NQ / 256, 256, 0, stream>>>(idx, oidx);
  k_gather<<<BB * DDIM, 256, 0, stream>>>(embT, idx, out);
  k_final<<<1, 256, 0, stream>>>(hist, lossp, out2);
}